// Round 5
// baseline (82.569 us; speedup 1.0000x reference)
//
#include <hip/hip_runtime.h>
#include <math.h>

// Problem constants (match reference)
#define B_ROWS 4096
#define D_DIM  512
#define N_ROWS 8192
#define R_NEG  4
#define NPAIRS B_ROWS              // pair (p, p+B): shared positive dot
#define NBLOCKS (NPAIRS / 4)       // 4 waves/block, one wave per PAIR -> 1024

// 1/(TEMPERATURE + EPSILON): fp32(1/(0.5+1e-8)) == 2.0f (verified absmax 0.0)
#define INV_T 2.0f

__device__ __forceinline__ float dot4(float4 a, float4 b) {
  return a.x * b.x + a.y * b.y + a.z * b.z + a.w * b.w;
}

// ---------------------------------------------------------------------------
// Kernel 1: one wave per ROW-PAIR (p, p+B).
//  - sim(p, p+B) == sim(p+B, p): the positive dot uses the two a-rows already
//    in registers -> both positive gathers deleted (96 MB -> 80 MB traffic).
//  - norms fused (a.a alongside a.b), 19 parallel shfl reductions.
//  - plain store per block (no atomics: 2048 same-address atomicAdds cost
//    ~18 us tail in R3; no __threadfence: L2 writeback thrashed L2 in R2).
// ---------------------------------------------------------------------------
__global__ __launch_bounds__(256, 4) void fused_loss_kernel(
    const float* __restrict__ zi, const float* __restrict__ zj,
    const int* __restrict__ neg_idx, float* __restrict__ partials) {
  __shared__ float s_nll[4];

  const int wave = threadIdx.x >> 6;
  const int lane = threadIdx.x & 63;
  const int p    = blockIdx.x * 4 + wave;   // pair id = row in z_i
  const int r0   = p;                        // row p      (z_i)
  const int r1   = p + B_ROWS;               // row p+B    (z_j)

  // Negative column indices (wave-uniform -> scalar loads)
  const int4 nv0 = ((const int4*)neg_idx)[r0];
  const int4 nv1 = ((const int4*)neg_idx)[r1];
  int cols[8];
  cols[0] = nv0.x + (nv0.x >= r0 ? 1 : 0);   // skip-diagonal mapping
  cols[1] = nv0.y + (nv0.y >= r0 ? 1 : 0);
  cols[2] = nv0.z + (nv0.z >= r0 ? 1 : 0);
  cols[3] = nv0.w + (nv0.w >= r0 ? 1 : 0);
  cols[4] = nv1.x + (nv1.x >= r1 ? 1 : 0);
  cols[5] = nv1.y + (nv1.y >= r1 ? 1 : 0);
  cols[6] = nv1.z + (nv1.z >= r1 ? 1 : 0);
  cols[7] = nv1.w + (nv1.w >= r1 ? 1 : 0);

  const float4* a4_0 = (const float4*)(zi + (size_t)p * D_DIM);
  const float4* a4_1 = (const float4*)(zj + (size_t)p * D_DIM);
  float4 a00 = a4_0[lane], a01 = a4_0[lane + 64];
  float4 a10 = a4_1[lane], a11 = a4_1[lane + 64];

  // Issue all 16 gather loads before any use (memory-level parallelism)
  float4 b0[8], b1[8];
#pragma unroll
  for (int c = 0; c < 8; ++c) {
    const int col = cols[c];
    const float4* b4 =
        (col < B_ROWS) ? (const float4*)(zi + (size_t)col * D_DIM)
                       : (const float4*)(zj + (size_t)(col - B_ROWS) * D_DIM);
    b0[c] = b4[lane];
    b1[c] = b4[lane + 64];
  }

  // Per-lane partials: 2 self-norms, 1 shared positive dot, 8x (dot, norm)
  float aa0 = dot4(a00, a00) + dot4(a01, a01);
  float aa1 = dot4(a10, a10) + dot4(a11, a11);
  float ap  = dot4(a00, a10) + dot4(a01, a11);
  float ab[8], bb[8];
#pragma unroll
  for (int c = 0; c < 8; ++c) {
    const float4 aL0 = (c < 4) ? a00 : a10;
    const float4 aL1 = (c < 4) ? a01 : a11;
    ab[c] = dot4(aL0, b0[c]) + dot4(aL1, b1[c]);
    bb[c] = dot4(b0[c], b0[c]) + dot4(b1[c], b1[c]);
  }

  // 19 simultaneous wave reductions
#pragma unroll
  for (int off = 32; off > 0; off >>= 1) {
    aa0 += __shfl_down(aa0, off);
    aa1 += __shfl_down(aa1, off);
    ap  += __shfl_down(ap, off);
#pragma unroll
    for (int c = 0; c < 8; ++c) {
      ab[c] += __shfl_down(ab[c], off);
      bb[c] += __shfl_down(bb[c], off);
    }
  }

  if (lane == 0) {
    const float inv0 = 1.0f / fmaxf(sqrtf(aa0), 1e-8f);
    const float inv1 = 1.0f / fmaxf(sqrtf(aa1), 1e-8f);
    const float pos  = ap * inv0 * inv1 * INV_T;  // shared by both rows

    float nll_sum = 0.0f;
#pragma unroll
    for (int r = 0; r < 2; ++r) {
      const float inv_a = (r == 0) ? inv0 : inv1;
      float logits[5];
      logits[0] = pos;
      float m = pos;
#pragma unroll
      for (int k = 0; k < 4; ++k) {
        const int c = r * 4 + k;
        const float inv_b = 1.0f / fmaxf(sqrtf(bb[c]), 1e-8f);
        logits[k + 1] = ab[c] * inv_a * inv_b * INV_T;
        m = fmaxf(m, logits[k + 1]);
      }
      float sum = 0.0f;
#pragma unroll
      for (int c = 0; c < 5; ++c) sum += __expf(logits[c] - m);
      nll_sum += -(logits[0] - m - __logf(sum));
    }
    s_nll[wave] = nll_sum;
  }
  __syncthreads();

  if (threadIdx.x == 0) {
    partials[blockIdx.x] = s_nll[0] + s_nll[1] + s_nll[2] + s_nll[3];
  }
}

// ---------------------------------------------------------------------------
// Kernel 2: reduce 1024 partials -> mean -> out[0]. One block, 256 threads.
// ---------------------------------------------------------------------------
__global__ __launch_bounds__(256) void reduce_kernel(
    const float* __restrict__ partials, float* __restrict__ out) {
  __shared__ float smem[4];
  const int lane = threadIdx.x & 63;
  const int wave = threadIdx.x >> 6;
  float s = 0.0f;
#pragma unroll
  for (int i = 0; i < NBLOCKS / 256; ++i) s += partials[i * 256 + threadIdx.x];
#pragma unroll
  for (int off = 32; off > 0; off >>= 1) s += __shfl_down(s, off);
  if (lane == 0) smem[wave] = s;
  __syncthreads();
  if (threadIdx.x == 0) {
    out[0] = (smem[0] + smem[1] + smem[2] + smem[3]) * (1.0f / (float)N_ROWS);
  }
}

extern "C" void kernel_launch(void* const* d_in, const int* in_sizes, int n_in,
                              void* d_out, int out_size, void* d_ws,
                              size_t ws_size, hipStream_t stream) {
  const float* zi      = (const float*)d_in[0];
  const float* zj      = (const float*)d_in[1];
  const int*   neg_idx = (const int*)d_in[2];
  float* out = (float*)d_out;
  float* partials = (float*)d_ws;  // NBLOCKS floats, fully written every call

  fused_loss_kernel<<<dim3(NBLOCKS), dim3(256), 0, stream>>>(
      zi, zj, neg_idx, partials);
  reduce_kernel<<<dim3(1), dim3(256), 0, stream>>>(partials, out);
}

// Round 6
// 79.669 us; speedup vs baseline: 1.0364x; 1.0364x over previous
//
#include <hip/hip_runtime.h>
#include <math.h>

// Problem constants (match reference)
#define B_ROWS 4096
#define D_DIM  512
#define N_ROWS 8192
#define R_NEG  4
#define NBLOCKS (N_ROWS / 4)  // 4 waves/block, one wave per row

// 1/(TEMPERATURE + EPSILON): fp32(1/(0.5+1e-8)) == 2.0f (verified absmax 0.0)
#define INV_T 2.0f

__device__ __forceinline__ float dot4(float4 a, float4 b) {
  return a.x * b.x + a.y * b.y + a.z * b.z + a.w * b.w;
}

// ---------------------------------------------------------------------------
// Kernel 1: fused norms + gathered dots + log-softmax. ONE ROW PER WAVE.
// Design decisions (all measured this session):
//  - one row/wave, 32 VGPR, 8 waves/SIMD: latency-bound gather needs max TLP.
//    (R5's row-pair variant cut traffic 17% but halved occupancy: 79->83 us.)
//  - no atomics (2048 same-address atomicAdds = ~18 us serialized tail, R3)
//  - no __threadfence (device fence = L2 writeback; 2.3x overfetch + 81 us, R2)
//  - no __syncthreads: lane 0 of each wave stores nll[row] directly; block
//    retires without cross-wave barrier.
// ---------------------------------------------------------------------------
__global__ __launch_bounds__(256) void fused_loss_kernel(
    const float* __restrict__ zi, const float* __restrict__ zj,
    const int* __restrict__ neg_idx, float* __restrict__ nll_out) {
  const int wave = threadIdx.x >> 6;
  const int lane = threadIdx.x & 63;
  const int row  = blockIdx.x * 4 + wave;

  // Gathered column indices (wave-uniform)
  const int4 nv = ((const int4*)neg_idx)[row];
  int cols[5];
  cols[0] = (row + B_ROWS) & (N_ROWS - 1);       // positive column
  cols[1] = nv.x + (nv.x >= row ? 1 : 0);        // skip-diagonal mapping
  cols[2] = nv.y + (nv.y >= row ? 1 : 0);
  cols[3] = nv.z + (nv.z >= row ? 1 : 0);
  cols[4] = nv.w + (nv.w >= row ? 1 : 0);

  const float4* a4 =
      (row < B_ROWS) ? (const float4*)(zi + (size_t)row * D_DIM)
                     : (const float4*)(zj + (size_t)(row - B_ROWS) * D_DIM);
  float4 a0 = a4[lane];
  float4 a1 = a4[lane + 64];

  // Issue all 10 gather loads before any use (memory-level parallelism)
  float4 b0[5], b1[5];
#pragma unroll
  for (int c = 0; c < 5; ++c) {
    const int col = cols[c];
    const float4* b4 =
        (col < B_ROWS) ? (const float4*)(zi + (size_t)col * D_DIM)
                       : (const float4*)(zj + (size_t)(col - B_ROWS) * D_DIM);
    b0[c] = b4[lane];
    b1[c] = b4[lane + 64];
  }

  // Per-lane partial sums: a.a plus (a.b, b.b) per column — norms are free.
  float aa = dot4(a0, a0) + dot4(a1, a1);
  float ab[5], bb[5];
#pragma unroll
  for (int c = 0; c < 5; ++c) {
    ab[c] = dot4(a0, b0[c]) + dot4(a1, b1[c]);
    bb[c] = dot4(b0[c], b0[c]) + dot4(b1[c], b1[c]);
  }

  // 11 simultaneous wave reductions
#pragma unroll
  for (int off = 32; off > 0; off >>= 1) {
    aa += __shfl_down(aa, off);
#pragma unroll
    for (int c = 0; c < 5; ++c) {
      ab[c] += __shfl_down(ab[c], off);
      bb[c] += __shfl_down(bb[c], off);
    }
  }

  if (lane == 0) {
    const float inv_a = 1.0f / fmaxf(sqrtf(aa), 1e-8f);
    float logits[5];
    float m = -INFINITY;
#pragma unroll
    for (int c = 0; c < 5; ++c) {
      const float inv_b = 1.0f / fmaxf(sqrtf(bb[c]), 1e-8f);
      logits[c] = ab[c] * inv_a * inv_b * INV_T;
      m = fmaxf(m, logits[c]);
    }
    float sum = 0.0f;
#pragma unroll
    for (int c = 0; c < 5; ++c) sum += __expf(logits[c] - m);
    nll_out[row] = -(logits[0] - m - __logf(sum));
  }
}

// ---------------------------------------------------------------------------
// Kernel 2: reduce 8192 nll values -> mean -> out[0]. One block, 256 threads,
// float4 loads (8 per thread).
// ---------------------------------------------------------------------------
__global__ __launch_bounds__(256) void reduce_kernel(
    const float* __restrict__ nll, float* __restrict__ out) {
  __shared__ float smem[4];
  const int lane = threadIdx.x & 63;
  const int wave = threadIdx.x >> 6;
  const float4* p4 = (const float4*)nll;
  float s = 0.0f;
#pragma unroll
  for (int i = 0; i < N_ROWS / 4 / 256; ++i) {
    float4 v = p4[i * 256 + threadIdx.x];
    s += v.x + v.y + v.z + v.w;
  }
#pragma unroll
  for (int off = 32; off > 0; off >>= 1) s += __shfl_down(s, off);
  if (lane == 0) smem[wave] = s;
  __syncthreads();
  if (threadIdx.x == 0) {
    out[0] = (smem[0] + smem[1] + smem[2] + smem[3]) * (1.0f / (float)N_ROWS);
  }
}

extern "C" void kernel_launch(void* const* d_in, const int* in_sizes, int n_in,
                              void* d_out, int out_size, void* d_ws,
                              size_t ws_size, hipStream_t stream) {
  const float* zi      = (const float*)d_in[0];
  const float* zj      = (const float*)d_in[1];
  const int*   neg_idx = (const int*)d_in[2];
  float* out = (float*)d_out;
  float* nll = (float*)d_ws;  // N_ROWS floats, fully written every call

  fused_loss_kernel<<<dim3(NBLOCKS), dim3(256), 0, stream>>>(
      zi, zj, neg_idx, nll);
  reduce_kernel<<<dim3(1), dim3(256), 0, stream>>>(nll, out);
}